// Round 4
// baseline (228.809 us; speedup 1.0000x reference)
//
#include <hip/hip_runtime.h>

#define S_DIM 512
#define B_DIM 16384
#define A_DIM 2
#define BA (B_DIM * A_DIM)   // 32768
#define HID 16
#define EMB 8
#define NPART 1000
#define TABN (NPART * HID)   // 16000

// Kernel 1: emb_proj[p][j] = b1[j] + sum_k emb_table[p][k] * W1[2+k][j]
__global__ __launch_bounds__(256) void emb_proj_kernel(
    const float* __restrict__ emb_table, const float* __restrict__ W1,
    const float* __restrict__ b1, float* __restrict__ proj) {
  int idx = blockIdx.x * 256 + threadIdx.x;
  if (idx >= TABN) return;
  int p = idx >> 4;
  int j = idx & 15;
  float acc = b1[j];
#pragma unroll
  for (int k = 0; k < EMB; ++k)
    acc = fmaf(emb_table[p * EMB + k], W1[(2 + k) * HID + j], acc);
  proj[idx] = acc;
}

// DPP quad-perm lane exchange: pure VALU, replaces ds_bpermute shuffles.
template <int CTRL>
__device__ __forceinline__ float qperm(float x) {
  return __builtin_bit_cast(
      float, __builtin_amdgcn_update_dpp(0, __builtin_bit_cast(int, x), CTRL,
                                         0xF, 0xF, true));
}

// Kernel 2: sequential scan. 4 lanes per (b,a) chain, 4 hidden units each.
// No LDS: 64KB proj table is L1/L2 resident; address known a step ahead.
__global__ __launch_bounds__(256) void scan_kernel(
    const int* __restrict__ act, const float* __restrict__ rew,
    const int* __restrict__ pid, const float* __restrict__ W1,
    const float* __restrict__ W2, const float* __restrict__ b2,
    const float* __restrict__ proj, float* __restrict__ out) {
  int t = blockIdx.x * 256 + threadIdx.x;  // 0 .. 131071
  int chain = t >> 2;                      // 0 .. 32767 (= b*A + a)
  int sub = t & 3;                         // 4-unit group of HID=16
  int b = chain >> 1;
  int j0 = sub << 2;

  float4 wa = *(const float4*)(W1 + j0);        // W1[0][j0..j0+3]
  float4 wb = *(const float4*)(W1 + HID + j0);  // W1[1][j0..j0+3]
  float4 w2 = *(const float4*)(W2 + j0);        // W2[j0..j0+3][0]
  float bb2 = b2[0];

  const float* rp = rew + chain;
  const int* ap = act + chain;
  const int* pp = pid + b;
  const float* tb = proj + j0;

  // software pipeline: r/a/p two steps ahead, table one step ahead
  float r0 = rp[0];
  float r1 = rp[BA];
  int a0 = ap[0];
  int a1 = ap[BA];
  int p1 = pp[B_DIM];                            // pid for step 1
  float4 tc = *(const float4*)(tb + pp[0] * HID);  // table row for step 0
  float state = 0.f;

  for (int s = 0; s < S_DIM; ++s) {
    float4 tn = *(const float4*)(tb + p1 * HID);  // table row for s+1
    int s2 = (s + 2 < S_DIM) ? s + 2 : S_DIM - 1; // clamped prefetch index
    float rN = rp[(size_t)s2 * BA];
    int aN = ap[(size_t)s2 * BA];
    int pN = pp[(size_t)s2 * B_DIM];

    // hidden units: h = tanh(max(x,0)) ; x = state*wa + r*wb + emb_proj
#define HUNIT(XW, XB, XT, XW2, MOUT)                                  \
    {                                                                 \
      float x_ = fmaf(state, XW, fmaf(r0, XB, XT));                   \
      x_ = fmaxf(x_, 0.f);                                            \
      float e_ = __builtin_amdgcn_exp2f(x_ * 2.8853900817779268f);    \
      float h_ = fmaf(-2.f, __builtin_amdgcn_rcpf(e_ + 1.f), 1.f);    \
      MOUT = h_ * XW2;                                                \
    }
    float m0, m1, m2, m3;
    HUNIT(wa.x, wb.x, tc.x, w2.x, m0);
    HUNIT(wa.y, wb.y, tc.y, w2.y, m1);
    HUNIT(wa.z, wb.z, tc.z, w2.z, m2);
    HUNIT(wa.w, wb.w, tc.w, w2.w, m3);
#undef HUNIT
    float psum = (m0 + m1) + (m2 + m3);
    // quad reduction via DPP (xor1, xor2) -- no DS pipe, no lgkm stall
    psum += qperm<0xB1>(psum);
    psum += qperm<0x4E>(psum);

    float z = state + bb2 + psum;
    z = (a0 == 1) ? z : state;
    state = __builtin_amdgcn_rcpf(
        1.f + __builtin_amdgcn_exp2f(z * -1.4426950408889634f));
    if (sub == 0) out[(size_t)s * BA + chain] = state;

    // rotate pipeline registers
    r0 = r1; a0 = a1;
    r1 = rN; a1 = aN;
    p1 = pN;
    tc = tn;
  }
}

extern "C" void kernel_launch(void* const* d_in, const int* in_sizes, int n_in,
                              void* d_out, int out_size, void* d_ws, size_t ws_size,
                              hipStream_t stream) {
  const int* c_Action = (const int*)d_in[0];
  const float* c_Reward = (const float*)d_in[1];
  const int* c_ParticipantID = (const int*)d_in[2];
  const float* emb_table = (const float*)d_in[3];
  const float* W1 = (const float*)d_in[4];
  const float* b1 = (const float*)d_in[5];
  const float* W2 = (const float*)d_in[6];
  const float* b2 = (const float*)d_in[7];
  float* out = (float*)d_out;
  float* proj = (float*)d_ws;  // 16000 floats = 64 KB scratch

  emb_proj_kernel<<<(TABN + 255) / 256, 256, 0, stream>>>(emb_table, W1, b1, proj);

  // 32768 chains * 4 lanes = 131072 threads; 512 blocks of 256
  scan_kernel<<<(BA * 4) / 256, 256, 0, stream>>>(
      c_Action, c_Reward, c_ParticipantID, W1, W2, b2, proj, out);
}

// Round 5
// 136.885 us; speedup vs baseline: 1.6715x; 1.6715x over previous
//
#include <hip/hip_runtime.h>

#define S_DIM 512
#define B_DIM 16384
#define A_DIM 2
#define BA (B_DIM * A_DIM)   // 32768
#define HID 16
#define EMB 8
#define NPART 1000
#define TABN (NPART * HID)   // 16000
#define NG (S_DIM / 4)       // 128 groups of 4 steps

// Kernel 1: emb_proj[p][j] = b1[j] + sum_k emb_table[p][k] * W1[2+k][j]
__global__ __launch_bounds__(256) void emb_proj_kernel(
    const float* __restrict__ emb_table, const float* __restrict__ W1,
    const float* __restrict__ b1, float* __restrict__ proj) {
  int idx = blockIdx.x * 256 + threadIdx.x;
  if (idx >= TABN) return;
  int p = idx >> 4;
  int j = idx & 15;
  float acc = b1[j];
#pragma unroll
  for (int k = 0; k < EMB; ++k)
    acc = fmaf(emb_table[p * EMB + k], W1[(2 + k) * HID + j], acc);
  proj[idx] = acc;
}

// DPP quad-perm: pure-VALU lane exchange within each quad.
template <int CTRL>
__device__ __forceinline__ int dppi(int x) {
  return __builtin_amdgcn_update_dpp(0, x, CTRL, 0xF, 0xF, true);
}
template <int CTRL>
__device__ __forceinline__ float dppf(float x) {
  return __builtin_bit_cast(float, dppi<CTRL>(__builtin_bit_cast(int, x)));
}
#define BC(K) ((K) | ((K) << 2) | ((K) << 4) | ((K) << 6))  // broadcast lane K of quad

// Kernel 2: sequential scan, 4 lanes/chain, 4 hidden units/lane.
// Group-of-4-steps load batching: lane `sub` loads step 4g+sub's r/a/pid
// (one load instr per stream per group), DPP-broadcast per step. Raw streams
// prefetched 2 groups ahead; pid->table gather issued 1 group ahead.
__global__ __launch_bounds__(256) void scan_kernel(
    const int* __restrict__ act, const float* __restrict__ rew,
    const int* __restrict__ pid, const float* __restrict__ W1,
    const float* __restrict__ W2, const float* __restrict__ b2,
    const float* __restrict__ proj, float* __restrict__ out) {
  int t = blockIdx.x * 256 + threadIdx.x;  // 0 .. 131071
  int chain = t >> 2;                      // 0 .. 32767 (= b*A + a)
  int sub = t & 3;
  int b = chain >> 1;
  int j0 = sub << 2;

  float4 wa = *(const float4*)(W1 + j0);        // W1[0][j]
  float4 wb = *(const float4*)(W1 + HID + j0);  // W1[1][j]
  float4 w2 = *(const float4*)(W2 + j0);        // W2[j][0]
  float bb2 = b2[0];

  const float* rp = rew + chain;
  const int* ap = act + chain;
  const int* pp = pid + b;
  const float* tb = proj + j0;
  float* op = out + chain;

// one load per stream per group: lane sub covers step 4*G_+sub
#define LOAD_RAW(G_, RD, AD, PD)              \
  {                                           \
    int gg_ = (G_) < NG ? (G_) : NG - 1;      \
    size_t st_ = (size_t)(gg_ * 4 + sub);     \
    RD = rp[st_ * BA];                        \
    AD = ap[st_ * BA];                        \
    PD = pp[st_ * B_DIM];                     \
  }

// dependent table gather for one group: broadcast each step's pid, load row
#define ISSUE_TAB(PS, T0, T1, T2, T3)         \
  {                                           \
    int p0_ = dppi<BC(0)>(PS);                \
    int p1_ = dppi<BC(1)>(PS);                \
    int p2_ = dppi<BC(2)>(PS);                \
    int p3_ = dppi<BC(3)>(PS);                \
    T0 = *(const float4*)(tb + p0_ * HID);    \
    T1 = *(const float4*)(tb + p1_ * HID);    \
    T2 = *(const float4*)(tb + p2_ * HID);    \
    T3 = *(const float4*)(tb + p3_ * HID);    \
  }

#define HUNIT(XW, XB, XT, XW2, MOUT)                                \
  {                                                                 \
    float x_ = fmaf(state, XW, fmaf(r_, XB, XT));                   \
    x_ = fmaxf(x_, 0.f);                                            \
    float e_ = __builtin_amdgcn_exp2f(x_ * 2.8853900817779268f);    \
    float hh_ = fmaf(-2.f, __builtin_amdgcn_rcpf(e_ + 1.f), 1.f);   \
    MOUT = hh_ * XW2;                                               \
  }

#define STEP(K, T, HOUT)                                            \
  {                                                                 \
    float r_ = dppf<BC(K)>(rA);                                     \
    int a_ = dppi<BC(K)>(aA);                                       \
    float m0, m1, m2, m3;                                           \
    HUNIT(wa.x, wb.x, T.x, w2.x, m0);                               \
    HUNIT(wa.y, wb.y, T.y, w2.y, m1);                               \
    HUNIT(wa.z, wb.z, T.z, w2.z, m2);                               \
    HUNIT(wa.w, wb.w, T.w, w2.w, m3);                               \
    float ps = (m0 + m1) + (m2 + m3);                               \
    ps += dppf<0xB1>(ps); /* xor1 */                                \
    ps += dppf<0x4E>(ps); /* xor2 */                                \
    float z = state + bb2 + ps;                                     \
    z = (a_ == 1) ? z : state;                                      \
    state = __builtin_amdgcn_rcpf(                                  \
        1.f + __builtin_amdgcn_exp2f(z * -1.4426950408889634f));    \
    HOUT = state;                                                   \
  }

  float rA, rB, rC;
  int aA, aB, aC, pA, pB, pC;
  float4 t0, t1, t2, t3, u0, u1, u2, u3;

  LOAD_RAW(0, rA, aA, pA);
  LOAD_RAW(1, rB, aB, pB);
  ISSUE_TAB(pA, t0, t1, t2, t3);  // one-time full-latency stall

  float state = 0.f;
  float h0, h1, h2, h3;

  for (int g = 0; g < NG; ++g) {
    LOAD_RAW(g + 2, rC, aC, pC);       // 2-group (~8-step) lead
    ISSUE_TAB(pB, u0, u1, u2, u3);     // 1-group lead for the gather
    STEP(0, t0, h0);
    STEP(1, t1, h1);
    STEP(2, t2, h2);
    STEP(3, t3, h3);
    // batched store: lane sub writes step 4g+sub (all lanes active)
    float sv = (sub & 1) ? h1 : h0;
    float sw = (sub & 1) ? h3 : h2;
    sv = (sub & 2) ? sw : sv;
    op[(size_t)(g * 4 + sub) * BA] = sv;
    // rotate pipeline
    rA = rB; aA = aB; pA = pB;
    rB = rC; aB = aC; pB = pC;
    t0 = u0; t1 = u1; t2 = u2; t3 = u3;
  }
}

extern "C" void kernel_launch(void* const* d_in, const int* in_sizes, int n_in,
                              void* d_out, int out_size, void* d_ws, size_t ws_size,
                              hipStream_t stream) {
  const int* c_Action = (const int*)d_in[0];
  const float* c_Reward = (const float*)d_in[1];
  const int* c_ParticipantID = (const int*)d_in[2];
  const float* emb_table = (const float*)d_in[3];
  const float* W1 = (const float*)d_in[4];
  const float* b1 = (const float*)d_in[5];
  const float* W2 = (const float*)d_in[6];
  const float* b2 = (const float*)d_in[7];
  float* out = (float*)d_out;
  float* proj = (float*)d_ws;  // 16000 floats = 64 KB scratch

  emb_proj_kernel<<<(TABN + 255) / 256, 256, 0, stream>>>(emb_table, W1, b1, proj);

  // 32768 chains * 4 lanes = 131072 threads; 512 blocks of 256
  scan_kernel<<<(BA * 4) / 256, 256, 0, stream>>>(
      c_Action, c_Reward, c_ParticipantID, W1, W2, b2, proj, out);
}